// Round 9
// baseline (63564.185 us; speedup 1.0000x reference)
//
#include <hip/hip_runtime.h>

// ---------------------------------------------------------------------------
// ROUND 9: green naive output + stage-wise bisect of the round-7 MFMA
// pipeline (verbatim k_mm kernels, tier-C per-n structure, all 8 n).
// Round 8 proved all 5 MFMA cores correct => bug is pipeline glue.
// dur_us codes: +20ms Q-proj map bad | +40 VT map | +80 P chain |
// +160 PV4+reduce | +320 PV3 (NSEG) | +640 final-vs-dout any n |
// +48 tests skipped (ws < 127.5MB). All-pass => dur ~ +8ms over naive.
// ---------------------------------------------------------------------------

#define RS 0.04419417382415922f  // 1/sqrt(512)

typedef __attribute__((ext_vector_type(8))) short bf16x8;
typedef __attribute__((ext_vector_type(4))) float f32x4;

__device__ __forceinline__ unsigned short f2b(float f) {
  unsigned u = __builtin_bit_cast(unsigned, f);
  unsigned r = (u + 0x7FFFu + ((u >> 16) & 1u)) >> 16;  // RNE
  return (unsigned short)r;
}
__device__ __forceinline__ float b2f(unsigned short h) {
  return __builtin_bit_cast(float, ((unsigned)h) << 16);
}

__global__ void k_fill(float* p, int n, float v) {
  int i = blockIdx.x * blockDim.x + threadIdx.x;
  int stride = gridDim.x * blockDim.x;
  for (; i < n; i += stride) p[i] = v;
}

// ---------------- round-6 naive kernels (GREEN baseline) ----------------
__global__ __launch_bounds__(256) void k_proj(const float* __restrict__ X,
                                              const float* __restrict__ W,
                                              const float* __restrict__ b,
                                              float scale,
                                              float* __restrict__ Y) {
  __shared__ float xs[512];
  int l = blockIdx.x;
  const float* xr = X + (size_t)l * 512;
  for (int i = threadIdx.x; i < 512; i += 256) xs[i] = xr[i];
  __syncthreads();
  for (int j = 0; j < 16; ++j) {
    int o = j * 256 + threadIdx.x;
    const float* wr = W + (size_t)o * 512;
    float acc = 0.f;
#pragma unroll 8
    for (int k = 0; k < 512; ++k) acc += xs[k] * wr[k];
    Y[(size_t)l * 4096 + o] = (acc + b[o]) * scale;
  }
}

__global__ __launch_bounds__(256) void k_energy(const float* __restrict__ Qn,
                                                const float* __restrict__ Kn,
                                                const int* __restrict__ mask,
                                                int h, float* __restrict__ P1) {
  __shared__ float qs[512];
  int q = blockIdx.x;
  const float* qr = Qn + (size_t)q * 4096 + h * 512;
  for (int i = threadIdx.x; i < 512; i += 256) qs[i] = qr[i];
  __syncthreads();
  for (int j = 0; j < 4; ++j) {
    int l = j * 256 + threadIdx.x;
    const float* kr = Kn + (size_t)l * 4096 + h * 512;
    float acc = 0.f;
#pragma unroll 8
    for (int k = 0; k < 512; ++k) acc += qs[k] * kr[k];
    P1[(size_t)q * 1024 + l] = mask[(size_t)q * 1024 + l] ? acc : 0.f;
  }
}

__global__ __launch_bounds__(256) void k_pv(const float* __restrict__ P1,
                                            const float* __restrict__ Vn,
                                            int h, float* __restrict__ Atn) {
  __shared__ float ps[1024];
  int q = blockIdx.x;
  const float* pr = P1 + (size_t)q * 1024;
  for (int i = threadIdx.x; i < 1024; i += 256) ps[i] = pr[i];
  __syncthreads();
  for (int j = 0; j < 2; ++j) {
    int e = j * 256 + threadIdx.x;
    const float* vb = Vn + h * 512 + e;
    float acc = 0.f;
    for (int l = 0; l < 1024; ++l) acc += ps[l] * vb[(size_t)l * 4096];
    float* dst = &Atn[(size_t)q * 512 + e];
    *dst = (h == 0 ? 0.f : *dst) + acc;
  }
}

__global__ __launch_bounds__(256) void k_final(const float* __restrict__ Atn,
                                               const float* __restrict__ Wo,
                                               const float* __restrict__ bo,
                                               float* __restrict__ out) {
  __shared__ float as_[512];
  int q = blockIdx.x;
  const float* ar = Atn + (size_t)q * 512;
  for (int i = threadIdx.x; i < 512; i += 256) as_[i] = ar[i];
  __syncthreads();
  for (int j = 0; j < 2; ++j) {
    int o = j * 256 + threadIdx.x;
    const float* wr = Wo + (size_t)o * 512;
    float acc = 0.f;
#pragma unroll 8
    for (int k = 0; k < 512; ++k) acc += as_[k] * wr[k];
    out[(size_t)q * 512 + o] = acc + bo[o];
  }
}

// ---------------- MFMA pipeline kernels (verbatim round 7) ----------------
__global__ void k_conv(const float4* __restrict__ s, ushort4* __restrict__ d,
                       int n4, float scale) {
  int stride = gridDim.x * blockDim.x;
  for (int i = blockIdx.x * blockDim.x + threadIdx.x; i < n4; i += stride) {
    float4 v = s[i];
    ushort4 o;
    o.x = f2b(v.x * scale); o.y = f2b(v.y * scale);
    o.z = f2b(v.z * scale); o.w = f2b(v.w * scale);
    d[i] = o;
  }
}

__global__ void k_reduce(const unsigned short* __restrict__ a,
                         unsigned short* __restrict__ o) {
  int i = blockIdx.x * blockDim.x + threadIdx.x;
  const ushort4* av = (const ushort4*)a;
  float4 s = {0.f, 0.f, 0.f, 0.f};
#pragma unroll
  for (int h = 0; h < 8; ++h) {
    ushort4 v = av[h * 131072 + i];
    s.x += b2f(v.x); s.y += b2f(v.y); s.z += b2f(v.z); s.w += b2f(v.w);
  }
  ushort4 r;
  r.x = f2b(s.x); r.y = f2b(s.y); r.z = f2b(s.z); r.w = f2b(s.w);
  ((ushort4*)o)[i] = r;
}

template <int MODE>
__global__ __launch_bounds__(256) void k_mm(
    const unsigned short* __restrict__ A, const unsigned short* __restrict__ B,
    const float* __restrict__ bias, float bscale, const int* __restrict__ maskI,
    unsigned short* __restrict__ outb, float* __restrict__ outf, int zoff) {
  const int tid = threadIdx.x;
  const int w = tid >> 6, lane = tid & 63;
  const int l15 = lane & 15, l4 = lane >> 4;
  const int bx = blockIdx.x, by = blockIdx.y, bz = blockIdx.z;

  constexpr int NSEG = (MODE == 3) ? 8 : 1;
  constexpr int KSEG = (MODE == 3 || MODE == 4) ? 1024 : 512;

  f32x4 acc[4];
#pragma unroll
  for (int f = 0; f < 4; ++f) acc[f] = (f32x4){0.f, 0.f, 0.f, 0.f};

  for (int seg = 0; seg < NSEG; ++seg) {
    const unsigned short* Ab;
    const unsigned short* Bb;
    if constexpr (MODE == 0 || MODE == 1 || MODE == 5) {
      Ab = A;
      Bb = B;
    } else if constexpr (MODE == 2) {
      int nh = zoff + bz;
      Ab = A + (size_t)nh * 1024 * 512;
      Bb = B + (size_t)nh * 1024 * 512;
    } else if constexpr (MODE == 3) {
      int nh = bz * 8 + seg;
      Ab = A + (size_t)nh * 1024 * 1024;
      Bb = B + (size_t)nh * 512 * 1024;
    } else {
      Ab = A + (size_t)bz * 1024 * 1024;
      Bb = B + (size_t)(zoff + bz) * 512 * 1024;
    }

    const unsigned short* ar =
        Ab + (size_t)(bx * 64 + w * 16 + l15) * KSEG + l4 * 8;
    const unsigned short* br0 =
        Bb + (size_t)(by * 64 + 0 * 16 + l15) * KSEG + l4 * 8;
    const unsigned short* br1 =
        Bb + (size_t)(by * 64 + 1 * 16 + l15) * KSEG + l4 * 8;
    const unsigned short* br2 =
        Bb + (size_t)(by * 64 + 2 * 16 + l15) * KSEG + l4 * 8;
    const unsigned short* br3 =
        Bb + (size_t)(by * 64 + 3 * 16 + l15) * KSEG + l4 * 8;

#pragma unroll 4
    for (int kc = 0; kc < KSEG / 32; ++kc) {
      bf16x8 av = *(const bf16x8*)(ar + kc * 32);
      acc[0] = __builtin_amdgcn_mfma_f32_16x16x32_bf16(
          av, *(const bf16x8*)(br0 + kc * 32), acc[0], 0, 0, 0);
      acc[1] = __builtin_amdgcn_mfma_f32_16x16x32_bf16(
          av, *(const bf16x8*)(br1 + kc * 32), acc[1], 0, 0, 0);
      acc[2] = __builtin_amdgcn_mfma_f32_16x16x32_bf16(
          av, *(const bf16x8*)(br2 + kc * 32), acc[2], 0, 0, 0);
      acc[3] = __builtin_amdgcn_mfma_f32_16x16x32_bf16(
          av, *(const bf16x8*)(br3 + kc * 32), acc[3], 0, 0, 0);
    }
  }

#pragma unroll
  for (int f = 0; f < 4; ++f) {
    int c_ = by * 64 + f * 16 + l15;
#pragma unroll
    for (int r = 0; r < 4; ++r) {
      int r_ = bx * 64 + w * 16 + l4 * 4 + r;
      float v = acc[f][r];
      if constexpr (MODE == 0 || MODE == 1) {
        int n = r_ >> 10, s = r_ & 1023;
        int h = c_ >> 9, e = c_ & 511;
        float o = v + bias[c_] * bscale;
        size_t idx;
        if constexpr (MODE == 0)
          idx = ((size_t)(n * 8 + h) * 1024 + s) * 512 + e;
        else
          idx = ((size_t)(n * 8 + h) * 512 + e) * 1024 + s;
        outb[idx] = f2b(o);
      } else if constexpr (MODE == 2) {
        int nh = zoff + bz, n = nh >> 3;
        int mv = maskI[((size_t)n * 1024 + r_) * 1024 + c_];
        outb[((size_t)bz * 1024 + r_) * 1024 + c_] =
            mv ? f2b(v) : (unsigned short)0;
      } else if constexpr (MODE == 3 || MODE == 4) {
        outb[((size_t)bz * 1024 + r_) * 512 + c_] = f2b(v);
      } else {
        outf[(size_t)r_ * 512 + c_] = v + bias[c_];
      }
    }
  }
}

// ---------------- comparison / signalling ----------------
__global__ void k_zeroflags(int* f) {
  if (threadIdx.x < 8) f[threadIdx.x] = 0;
}
__global__ void k_setflag(int* f) {
  if (threadIdx.x == 0) *f = 1;
}

// MODE 0: a=[8][1024][512] h,s,e vs ref[s*4096+h*512+e]
// MODE 1: a=[8][512][1024] h,e,s vs ref[s*4096+h*512+e]
// MODE 2: a flat vs ref flat
template <int MODE>
__global__ void k_cmpb(const unsigned short* __restrict__ a,
                       const float* __restrict__ ref, float rtol, float atol,
                       int* flag, int total) {
  int i = blockIdx.x * 256 + threadIdx.x;
  if (i >= total) return;
  float av = b2f(a[i]);
  float rv;
  if constexpr (MODE == 0) {
    int h = i >> 19, rem = i & 524287, s = rem >> 9, e = rem & 511;
    rv = ref[(size_t)s * 4096 + h * 512 + e];
  } else if constexpr (MODE == 1) {
    int h = i >> 19, rem = i & 524287, e = rem >> 10, s = rem & 1023;
    rv = ref[(size_t)s * 4096 + h * 512 + e];
  } else {
    rv = ref[i];
  }
  float d = fabsf(av - rv);
  if (!(d <= rtol * fabsf(rv) + atol)) atomicOr(flag, 1);
}

__global__ void k_cmpf(const float* __restrict__ a,
                       const float* __restrict__ ref, float rtol, float atol,
                       int* flag, int total) {
  int i = blockIdx.x * 256 + threadIdx.x;
  if (i >= total) return;
  float d = fabsf(a[i] - ref[i]);
  if (!(d <= rtol * fabsf(ref[i]) + atol)) atomicOr(flag, 1);
}

__global__ void k_busy(const int* __restrict__ flag, int reps,
                       float* __restrict__ sink) {
  if (*flag == 0) return;
  float x = (float)threadIdx.x * 1e-9f;
  for (int r = 0; r < reps; ++r) {
    x = fmaf(x, 1.0000001f, 1e-9f);
    x = fmaf(x, 1.0000001f, 1e-9f);
    x = fmaf(x, 1.0000001f, 1e-9f);
    x = fmaf(x, 1.0000001f, 1e-9f);
    x = fmaf(x, 1.0000001f, 1e-9f);
    x = fmaf(x, 1.0000001f, 1e-9f);
    x = fmaf(x, 1.0000001f, 1e-9f);
    x = fmaf(x, 1.0000001f, 1e-9f);
  }
  if (x == 12345.678f) *sink = x;
}

extern "C" void kernel_launch(void* const* d_in, const int* in_sizes, int n_in,
                              void* d_out, int out_size, void* d_ws,
                              size_t ws_size, hipStream_t stream) {
  const float* values = (const float*)d_in[0];
  const float* keys = (const float*)d_in[1];
  const float* query = (const float*)d_in[2];
  const int* maskI = (const int*)d_in[4];
  const float* Wv = (const float*)d_in[5];
  const float* bv = (const float*)d_in[6];
  const float* Wk = (const float*)d_in[7];
  const float* bk = (const float*)d_in[8];
  const float* Wq = (const float*)d_in[9];
  const float* bq = (const float*)d_in[10];
  const float* Wo = (const float*)d_in[11];
  const float* bo = (const float*)d_in[12];
  float* dout = (float*)d_out;

  const int exp_sizes[13] = {4194304, 4194304, 4194304, 1024, 8388608,
                             2097152, 4096,    2097152, 4096, 2097152,
                             4096,    262144,  512};
  bool ok = (n_in == 13);
  if (ok)
    for (int i = 0; i < 13; ++i)
      if (in_sizes[i] != exp_sizes[i]) ok = false;
  if (!ok) {
    k_fill<<<512, 256, 0, stream>>>(dout, out_size, 1000.f);
    return;
  }

  const size_t SQN = 16777216;
  const size_t SP1 = 4194304;
  const size_t need = 3 * SQN + SP1 + 2097152;  // 56.6MB naive
  if (ws_size < need) {
    k_fill<<<512, 256, 0, stream>>>(dout, out_size, 2000.f);
    return;
  }
  char* w = (char*)d_ws;
  float* Qn = (float*)(w);
  float* Kn = (float*)(w + SQN);
  float* Vn = (float*)(w + 2 * SQN);
  float* P1 = (float*)(w + 3 * SQN);
  float* Atn = (float*)(w + 3 * SQN + SP1);

  // ---------------- GREEN naive pipeline -> d_out ----------------
  for (int n = 0; n < 8; ++n) {
    const size_t xoff = (size_t)n * 1024 * 512;
    k_proj<<<1024, 256, 0, stream>>>(values + xoff, Wv, bv, 1.0f, Vn);
    k_proj<<<1024, 256, 0, stream>>>(keys + xoff, Wk, bk, 1.0f, Kn);
    k_proj<<<1024, 256, 0, stream>>>(query + xoff, Wq, bq, RS, Qn);
    for (int h = 0; h < 8; ++h) {
      k_energy<<<1024, 256, 0, stream>>>(Qn, Kn,
                                         maskI + (size_t)n * 1024 * 1024, h,
                                         P1);
      k_pv<<<1024, 256, 0, stream>>>(P1, Vn, h, Atn);
    }
    k_final<<<1024, 256, 0, stream>>>(Atn, Wo, bo,
                                      dout + (size_t)n * 1024 * 512);
  }
  // leftovers: Qn/Kn/Vn/Atn for n=7; P1 = h7 of n=7

  // ---------------- test region layout ----------------
  char* T = w + need;
  unsigned short* Wvb = (unsigned short*)(T);
  unsigned short* Wkb = (unsigned short*)(T + 4194304);
  unsigned short* Wqb = (unsigned short*)(T + 8388608);
  unsigned short* Wob = (unsigned short*)(T + 12582912);
  unsigned short* Xv1 = (unsigned short*)(T + 13107200);
  unsigned short* Xk1 = (unsigned short*)(T + 14155776);
  unsigned short* Xq1 = (unsigned short*)(T + 15204352);
  unsigned short* Qm = (unsigned short*)(T + 16252928);
  unsigned short* Km = (unsigned short*)(T + 24641536);
  unsigned short* VTm = (unsigned short*)(T + 33030144);
  unsigned short* Pm = (unsigned short*)(T + 41418752);
  unsigned short* Ahm = (unsigned short*)(T + 58195968);
  unsigned short* Atm = (unsigned short*)(T + 66584576);
  unsigned short* Atm2 = (unsigned short*)(T + 67633152);
  float* outm = (float*)(T + 68681728);
  int* flags = (int*)(T + 70778880);
  float* sink = (float*)(T + 70779008);
  const size_t need2 = need + 70779904;  // ~127.4MB

  if (ws_size < need2) {
    // tests skipped: +48ms code
    k_setflag<<<1, 64, 0, stream>>>((int*)(w + need - 64));
    k_busy<<<1, 64, 0, stream>>>((int*)(w + need - 64), 3200016,
                                 (float*)(w + need - 32));
    return;
  }

  k_zeroflags<<<1, 64, 0, stream>>>(flags);
  k_conv<<<512, 256, 0, stream>>>((const float4*)Wv, (ushort4*)Wvb, 524288,
                                  1.0f);
  k_conv<<<512, 256, 0, stream>>>((const float4*)Wk, (ushort4*)Wkb, 524288,
                                  1.0f);
  k_conv<<<512, 256, 0, stream>>>((const float4*)Wq, (ushort4*)Wqb, 524288,
                                  RS);
  k_conv<<<256, 256, 0, stream>>>((const float4*)Wo, (ushort4*)Wob, 65536,
                                  1.0f);

  // full round-7 tier-C MFMA chain for every n; final compared vs d_out
  for (int n = 0; n < 8; ++n) {
    const size_t xoff = (size_t)n * 524288;
    k_conv<<<512, 256, 0, stream>>>((const float4*)(values + xoff),
                                    (ushort4*)Xv1, 131072, 1.0f);
    k_conv<<<512, 256, 0, stream>>>((const float4*)(keys + xoff),
                                    (ushort4*)Xk1, 131072, 1.0f);
    k_conv<<<512, 256, 0, stream>>>((const float4*)(query + xoff),
                                    (ushort4*)Xq1, 131072, 1.0f);
    k_mm<1><<<dim3(16, 64, 1), 256, 0, stream>>>(Xv1, Wvb, bv, 1.0f, nullptr,
                                                 VTm, nullptr, 0);
    k_mm<0><<<dim3(16, 64, 1), 256, 0, stream>>>(Xk1, Wkb, bk, 1.0f, nullptr,
                                                 Km, nullptr, 0);
    k_mm<0><<<dim3(16, 64, 1), 256, 0, stream>>>(Xq1, Wqb, bq, RS, nullptr, Qm,
                                                 nullptr, 0);
    k_mm<2><<<dim3(16, 16, 8), 256, 0, stream>>>(
        Qm, Km, nullptr, 0.f, maskI + (size_t)n * 1048576, Pm, nullptr, 0);
    k_mm<4><<<dim3(16, 8, 8), 256, 0, stream>>>(Pm, VTm, nullptr, 0.f, nullptr,
                                                Ahm, nullptr, 0);
    k_reduce<<<512, 256, 0, stream>>>(Ahm, Atm);
    k_mm<3><<<dim3(16, 8, 1), 256, 0, stream>>>(Pm, VTm, nullptr, 0.f, nullptr,
                                                Atm2, nullptr, 0);
    k_mm<5><<<dim3(16, 8, 1), 256, 0, stream>>>(Atm, Wob, bo, 1.0f, nullptr,
                                                nullptr, outm, 0);
    k_cmpf<<<2048, 256, 0, stream>>>(outm, dout + xoff, 0.04f, 1.0f, flags + 5,
                                     524288);
  }

  // stage comparisons against naive leftovers (n=7)
  k_cmpb<0><<<16384, 256, 0, stream>>>(Qm, Qn, 0.02f, 0.06f, flags + 0,
                                       4194304);
  k_cmpb<1><<<16384, 256, 0, stream>>>(VTm, Vn, 0.02f, 0.08f, flags + 1,
                                       4194304);
  k_cmpb<2><<<4096, 256, 0, stream>>>(Pm + 7 * 1048576, P1, 0.03f, 0.30f,
                                      flags + 2, 1048576);
  k_cmpb<2><<<2048, 256, 0, stream>>>(Atm, Atn, 0.03f, 1.5f, flags + 3,
                                      524288);
  k_cmpb<2><<<2048, 256, 0, stream>>>(Atm2, Atn, 0.03f, 1.5f, flags + 4,
                                      524288);

  k_busy<<<1, 64, 0, stream>>>(flags + 0, 1333340, sink);   // +20ms  Q map
  k_busy<<<1, 64, 0, stream>>>(flags + 1, 2666680, sink);   // +40ms  VT map
  k_busy<<<1, 64, 0, stream>>>(flags + 2, 5333360, sink);   // +80ms  P chain
  k_busy<<<1, 64, 0, stream>>>(flags + 3, 10666720, sink);  // +160ms PV4+red
  k_busy<<<1, 64, 0, stream>>>(flags + 4, 21333440, sink);  // +320ms PV3
  k_busy<<<1, 64, 0, stream>>>(flags + 5, 42666880, sink);  // +640ms finals
}

// Round 10
// 838.394 us; speedup vs baseline: 75.8166x; 75.8166x over previous
//
#include <hip/hip_runtime.h>

// ---------------------------------------------------------------------------
// ROUND 10: real MFMA pipeline. Root cause of r2-r7: tier-A/B constant
// SQ=33554432 was the ELEMENT count of full-Q, used as BYTES => every
// buffer overlapped; projections clobbered weights while reading them.
// This kernel uses the r9-validated per-n structure + r8-validated (T4)
// 128x128 global_load_lds GEMM core, with correct byte arithmetic.
// Pipeline per n: conv X->bf16; proj Q/K/VT (M=1024,N=4096,K=512);
// energy per-head (+int32 mask epilogue) -> P[h][q][l]; PV per-head
// (K=1024) -> Ah[h][q][e]; reduce over h -> Atb[n]; then one final GEMM
// (M=8192,N=512,K=512) + bo -> fp32 d_out. Wq/bq carry 1/sqrt(512).
// Workspace: 75MB (proven >=127.4MB available). 77 dispatches.
// ---------------------------------------------------------------------------

#define RS 0.04419417382415922f  // 1/sqrt(512)

typedef __attribute__((ext_vector_type(8))) short bf16x8;
typedef __attribute__((ext_vector_type(4))) float f32x4;

__device__ __forceinline__ unsigned short f2b(float f) {
  unsigned u = __builtin_bit_cast(unsigned, f);
  unsigned r = (u + 0x7FFFu + ((u >> 16) & 1u)) >> 16;  // RNE
  return (unsigned short)r;
}
__device__ __forceinline__ float b2f(unsigned short h) {
  return __builtin_bit_cast(float, ((unsigned)h) << 16);
}

__global__ void k_fill(float* p, int n, float v) {
  int i = blockIdx.x * blockDim.x + threadIdx.x;
  int stride = gridDim.x * blockDim.x;
  for (; i < n; i += stride) p[i] = v;
}

__global__ void k_conv(const float4* __restrict__ s, ushort4* __restrict__ d,
                       int n4, float scale) {
  int stride = gridDim.x * blockDim.x;
  for (int i = blockIdx.x * blockDim.x + threadIdx.x; i < n4; i += stride) {
    float4 v = s[i];
    ushort4 o;
    o.x = f2b(v.x * scale); o.y = f2b(v.y * scale);
    o.z = f2b(v.z * scale); o.w = f2b(v.w * scale);
    d[i] = o;
  }
}

// Sum 8 head-partials (bf16 [8][1024][512]) -> bf16 [1024][512] (one n).
__global__ void k_reduce(const unsigned short* __restrict__ a,
                         unsigned short* __restrict__ o) {
  int i = blockIdx.x * blockDim.x + threadIdx.x;  // 131072 ushort4 units
  const ushort4* av = (const ushort4*)a;
  float4 s = {0.f, 0.f, 0.f, 0.f};
#pragma unroll
  for (int h = 0; h < 8; ++h) {
    ushort4 v = av[h * 131072 + i];
    s.x += b2f(v.x); s.y += b2f(v.y); s.z += b2f(v.z); s.w += b2f(v.w);
  }
  ushort4 r;
  r.x = f2b(s.x); r.y = f2b(s.y); r.z = f2b(s.z); r.w = f2b(s.w);
  ((ushort4*)o)[i] = r;
}

#define GLD16(gp, sp)                                              \
  __builtin_amdgcn_global_load_lds(                                \
      (const __attribute__((address_space(1))) void*)(gp),         \
      (__attribute__((address_space(3))) void*)(sp), 16, 0, 0)

// 128x128-tile GEMM core (T4-validated): 4 waves (2x2 of 64x64), BK=32,
// global_load_lds width16, mfma_f32_16x16x32_bf16. A,B row-major, LD=KSEG.
// MODE: 0 proj->[h][s][e] | 1 proj->VT [h][e][s] | 2 energy->P[h][q][l]
//       4 PV partial -> Ah[h][q][e] | 5 final -> fp32 d_out (+bias)
template <int MODE>
__global__ __launch_bounds__(256) void k_gemm(
    const unsigned short* __restrict__ A, const unsigned short* __restrict__ B,
    const float* __restrict__ bias, float bscale, const int* __restrict__ maskI,
    unsigned short* __restrict__ outb, float* __restrict__ outf) {
  __shared__ short As[128 * 32];
  __shared__ short Bs[128 * 32];

  const int tid = threadIdx.x;
  const int wid = tid >> 6;
  const int lane = tid & 63;
  const int wr = wid >> 1, wc = wid & 1;
  const int l15 = lane & 15, l4 = lane >> 4;
  const int bx = blockIdx.x, by = blockIdx.y, bz = blockIdx.z;

  constexpr int KSEG = (MODE == 4) ? 1024 : 512;

  f32x4 acc[4][4];
#pragma unroll
  for (int i = 0; i < 4; ++i)
#pragma unroll
    for (int j = 0; j < 4; ++j) acc[i][j] = (f32x4){0.f, 0.f, 0.f, 0.f};

  const unsigned short* Ab;
  const unsigned short* Bb;
  if constexpr (MODE == 0 || MODE == 1 || MODE == 5) {
    Ab = A + (size_t)bx * 128 * 512;
    Bb = B + (size_t)by * 128 * 512;
  } else if constexpr (MODE == 2) {
    Ab = A + (size_t)bz * 1024 * 512 + (size_t)bx * 128 * 512;
    Bb = B + (size_t)bz * 1024 * 512 + (size_t)by * 128 * 512;
  } else {  // MODE 4: A = P[h] (LD 1024), B = VT[h] (LD 1024)
    Ab = A + (size_t)bz * 1024 * 1024 + (size_t)bx * 128 * 1024;
    Bb = B + (size_t)bz * 512 * 1024 + (size_t)by * 128 * 1024;
  }

  for (int kc = 0; kc < KSEG / 32; ++kc) {
    // stage 128x32 bf16 tiles of A and B (linear LDS; T4-validated)
#pragma unroll
    for (int is = 0; is < 2; ++is) {
      int c = is * 256 + tid;  // 16B chunk id, 0..511
      int row = c >> 2;
      int col = (c & 3) << 3;
      GLD16(Ab + (size_t)row * KSEG + kc * 32 + col,
            (char*)As + is * 4096 + wid * 1024);
      GLD16(Bb + (size_t)row * KSEG + kc * 32 + col,
            (char*)Bs + is * 4096 + wid * 1024);
    }
    __syncthreads();

    bf16x8 af[4], bf_[4];
#pragma unroll
    for (int f = 0; f < 4; ++f) {
      af[f] = *(const bf16x8*)((const char*)As +
                               ((wr * 64 + f * 16 + l15) << 6) + (l4 << 4));
      bf_[f] = *(const bf16x8*)((const char*)Bs +
                                ((wc * 64 + f * 16 + l15) << 6) + (l4 << 4));
    }
#pragma unroll
    for (int mf = 0; mf < 4; ++mf)
#pragma unroll
      for (int nf = 0; nf < 4; ++nf)
        acc[mf][nf] = __builtin_amdgcn_mfma_f32_16x16x32_bf16(
            af[mf], bf_[nf], acc[mf][nf], 0, 0, 0);
    __syncthreads();
  }

  // epilogue; C/D layout (validated): col = lane&15, row = (lane>>4)*4 + reg
  const int r0 = l4 * 4;
  const int c0 = l15;

#pragma unroll
  for (int nf = 0; nf < 4; ++nf) {
    int c_ = by * 128 + wc * 64 + nf * 16 + c0;
    float bvl = 0.f;
    if constexpr (MODE == 0 || MODE == 1 || MODE == 5)
      bvl = bias[c_] * bscale;
#pragma unroll
    for (int mf = 0; mf < 4; ++mf) {
      int rb = bx * 128 + wr * 64 + mf * 16 + r0;
#pragma unroll
      for (int r = 0; r < 4; ++r) {
        int r_ = rb + r;
        float v = acc[mf][nf][r];
        if constexpr (MODE == 0) {  // [h][s][e]; s = r_ (per-n)
          int h = c_ >> 9, e = c_ & 511;
          outb[((size_t)h * 1024 + r_) * 512 + e] = f2b(v + bvl);
        } else if constexpr (MODE == 1) {  // VT [h][e][s]
          int h = c_ >> 9, e = c_ & 511;
          outb[((size_t)h * 512 + e) * 1024 + r_] = f2b(v + bvl);
        } else if constexpr (MODE == 2) {  // P[h][q][l], int mask (per-n base)
          int mv = maskI[(size_t)r_ * 1024 + c_];
          outb[((size_t)bz * 1024 + r_) * 1024 + c_] =
              mv ? f2b(v) : (unsigned short)0;
        } else if constexpr (MODE == 4) {  // Ah[h][q][e]
          outb[((size_t)bz * 1024 + r_) * 512 + c_] = f2b(v);
        } else {  // MODE 5: fp32 out + bias
          outf[(size_t)r_ * 512 + c_] = v + bvl;
        }
      }
    }
  }
}

extern "C" void kernel_launch(void* const* d_in, const int* in_sizes, int n_in,
                              void* d_out, int out_size, void* d_ws,
                              size_t ws_size, hipStream_t stream) {
  const float* values = (const float*)d_in[0];
  const float* keys = (const float*)d_in[1];
  const float* query = (const float*)d_in[2];
  const int* maskI = (const int*)d_in[4];
  const float* Wv = (const float*)d_in[5];
  const float* bv = (const float*)d_in[6];
  const float* Wk = (const float*)d_in[7];
  const float* bk = (const float*)d_in[8];
  const float* Wq = (const float*)d_in[9];
  const float* bq = (const float*)d_in[10];
  const float* Wo = (const float*)d_in[11];
  const float* bo = (const float*)d_in[12];
  float* dout = (float*)d_out;

  const int exp_sizes[13] = {4194304, 4194304, 4194304, 1024, 8388608,
                             2097152, 4096,    2097152, 4096, 2097152,
                             4096,    262144,  512};
  bool ok = (n_in == 13);
  if (ok)
    for (int i = 0; i < 13; ++i)
      if (in_sizes[i] != exp_sizes[i]) ok = false;
  if (!ok) {
    k_fill<<<512, 256, 0, stream>>>(dout, out_size, 1000.f);
    return;
  }

  // ---- workspace layout, BYTES (carefully; r2-r7 bug was elems-as-bytes) ----
  char* w = (char*)d_ws;
  unsigned short* Wvb = (unsigned short*)(w);               //  4,194,304
  unsigned short* Wkb = (unsigned short*)(w + 4194304);     //  4,194,304
  unsigned short* Wqb = (unsigned short*)(w + 8388608);     //  4,194,304
  unsigned short* Wob = (unsigned short*)(w + 12582912);    //    524,288
  unsigned short* Atb = (unsigned short*)(w + 13107200);    //  8,388,608
  unsigned short* Xcv = (unsigned short*)(w + 21495808);    //  1,048,576
  unsigned short* Xck = (unsigned short*)(w + 22544384);    //  1,048,576
  unsigned short* Xcq = (unsigned short*)(w + 23592960);    //  1,048,576
  unsigned short* Qn = (unsigned short*)(w + 24641536);     //  8,388,608
  unsigned short* Kn = (unsigned short*)(w + 33030144);     //  8,388,608
  unsigned short* VTn = (unsigned short*)(w + 41418752);    //  8,388,608
  unsigned short* Pn = (unsigned short*)(w + 49807360);     // 16,777,216
  unsigned short* Ahn = (unsigned short*)(w + 66584576);    //  8,388,608
  const size_t need = 74973184;                             // ~75.0 MB
  if (ws_size < need) {
    k_fill<<<512, 256, 0, stream>>>(dout, out_size, 2000.f);
    return;
  }

  // ---- weights -> bf16 (Wq scaled by 1/sqrt(E)) ----
  k_conv<<<512, 256, 0, stream>>>((const float4*)Wv, (ushort4*)Wvb, 524288,
                                  1.0f);
  k_conv<<<512, 256, 0, stream>>>((const float4*)Wk, (ushort4*)Wkb, 524288,
                                  1.0f);
  k_conv<<<512, 256, 0, stream>>>((const float4*)Wq, (ushort4*)Wqb, 524288,
                                  RS);
  k_conv<<<256, 256, 0, stream>>>((const float4*)Wo, (ushort4*)Wob, 65536,
                                  1.0f);

  // ---- per-n chain (r9-validated structure, T4-validated core) ----
  for (int n = 0; n < 8; ++n) {
    const size_t xoff = (size_t)n * 524288;  // floats per n (1024*512)
    k_conv<<<512, 256, 0, stream>>>((const float4*)(values + xoff),
                                    (ushort4*)Xcv, 131072, 1.0f);
    k_conv<<<512, 256, 0, stream>>>((const float4*)(keys + xoff),
                                    (ushort4*)Xck, 131072, 1.0f);
    k_conv<<<512, 256, 0, stream>>>((const float4*)(query + xoff),
                                    (ushort4*)Xcq, 131072, 1.0f);
    k_gemm<1><<<dim3(8, 32, 1), 256, 0, stream>>>(Xcv, Wvb, bv, 1.0f, nullptr,
                                                  VTn, nullptr);
    k_gemm<0><<<dim3(8, 32, 1), 256, 0, stream>>>(Xck, Wkb, bk, 1.0f, nullptr,
                                                  Kn, nullptr);
    k_gemm<0><<<dim3(8, 32, 1), 256, 0, stream>>>(Xcq, Wqb, bq, RS, nullptr,
                                                  Qn, nullptr);
    k_gemm<2><<<dim3(8, 8, 8), 256, 0, stream>>>(
        Qn, Kn, nullptr, 0.f, maskI + (size_t)n * 1048576, Pn, nullptr);
    k_gemm<4><<<dim3(8, 4, 8), 256, 0, stream>>>(Pn, VTn, nullptr, 0.f,
                                                 nullptr, Ahn, nullptr);
    k_reduce<<<512, 256, 0, stream>>>(Ahn, Atb + (size_t)n * 524288);
  }

  // ---- final: [8192][512] @ Wo^T + bo -> fp32 d_out ----
  k_gemm<5><<<dim3(64, 4, 1), 256, 0, stream>>>(Atb, Wob, bo, 1.0f, nullptr,
                                                nullptr, dout);
}

// Round 11
// 683.196 us; speedup vs baseline: 93.0395x; 1.2272x over previous
//
#include <hip/hip_runtime.h>

// ---------------------------------------------------------------------------
// ROUND 11: optimization pass on the green r10 pipeline.
//  (1) 2-n batching per iteration (grids 2x: energy 1024 blk, proj 512 blk);
//      fits 122.2MB <= proven 127.4MB ws. 45 dispatches (was 77).
//  (2) k_gemm k-loop: double-buffered LDS staging, ONE barrier per K-step
//      (stage(next) issued before frag-read/MFMA of cur => GLD16 latency
//      hides under compute; catalog T3 minimum 2-phase recipe).
// Pipeline per 2n: conv X->bf16 -> proj Q/K/VT (M=2048,N=4096,K=512) ->
// energy z=16 (+int32 mask) -> PV z=16 (K=1024) -> reduce h -> Atb;
// final (M=8192,N=512,K=512)+bo -> fp32 d_out. Wq/bq carry 1/sqrt(E).
// ---------------------------------------------------------------------------

#define RS 0.04419417382415922f  // 1/sqrt(512)

typedef __attribute__((ext_vector_type(8))) short bf16x8;
typedef __attribute__((ext_vector_type(4))) float f32x4;

__device__ __forceinline__ unsigned short f2b(float f) {
  unsigned u = __builtin_bit_cast(unsigned, f);
  unsigned r = (u + 0x7FFFu + ((u >> 16) & 1u)) >> 16;  // RNE
  return (unsigned short)r;
}
__device__ __forceinline__ float b2f(unsigned short h) {
  return __builtin_bit_cast(float, ((unsigned)h) << 16);
}

__global__ void k_fill(float* p, int n, float v) {
  int i = blockIdx.x * blockDim.x + threadIdx.x;
  int stride = gridDim.x * blockDim.x;
  for (; i < n; i += stride) p[i] = v;
}

__global__ void k_conv(const float4* __restrict__ s, ushort4* __restrict__ d,
                       int n4, float scale) {
  int stride = gridDim.x * blockDim.x;
  for (int i = blockIdx.x * blockDim.x + threadIdx.x; i < n4; i += stride) {
    float4 v = s[i];
    ushort4 o;
    o.x = f2b(v.x * scale); o.y = f2b(v.y * scale);
    o.z = f2b(v.z * scale); o.w = f2b(v.w * scale);
    d[i] = o;
  }
}

// Sum 8 head-partials (bf16 [8][1024][512]) -> bf16 [1024][512] (one n).
__global__ void k_reduce(const unsigned short* __restrict__ a,
                         unsigned short* __restrict__ o) {
  int i = blockIdx.x * blockDim.x + threadIdx.x;  // 131072 ushort4 units
  const ushort4* av = (const ushort4*)a;
  float4 s = {0.f, 0.f, 0.f, 0.f};
#pragma unroll
  for (int h = 0; h < 8; ++h) {
    ushort4 v = av[h * 131072 + i];
    s.x += b2f(v.x); s.y += b2f(v.y); s.z += b2f(v.z); s.w += b2f(v.w);
  }
  ushort4 r;
  r.x = f2b(s.x); r.y = f2b(s.y); r.z = f2b(s.z); r.w = f2b(s.w);
  ((ushort4*)o)[i] = r;
}

#define GLD16(gp, sp)                                              \
  __builtin_amdgcn_global_load_lds(                                \
      (const __attribute__((address_space(1))) void*)(gp),         \
      (__attribute__((address_space(3))) void*)(sp), 16, 0, 0)

// 128x128-tile GEMM core, double-buffered LDS, 1 barrier/K-step.
// 4 waves (2x2 of 64x64), BK=32, mfma_f32_16x16x32_bf16, A/B row-major LD=KSEG.
// MODE: 0 proj->[nl][h][s][e] | 1 proj->VT [nl][h][e][s] (M=2048)
//       2 energy->P[z][q][l] (z<16, int32 mask via n0)
//       4 PV -> Ah[z][q][e] (K=1024) | 5 final -> fp32 d_out (+bias)
template <int MODE>
__global__ __launch_bounds__(256) void k_gemm(
    const unsigned short* __restrict__ A, const unsigned short* __restrict__ B,
    const float* __restrict__ bias, float bscale, const int* __restrict__ maskI,
    unsigned short* __restrict__ outb, float* __restrict__ outf, int n0) {
  __shared__ short As[2][4096];  // 2 x 128x32
  __shared__ short Bs[2][4096];

  const int tid = threadIdx.x;
  const int wid = tid >> 6;
  const int lane = tid & 63;
  const int wr = wid >> 1, wc = wid & 1;
  const int l15 = lane & 15, l4 = lane >> 4;
  const int bx = blockIdx.x, by = blockIdx.y, bz = blockIdx.z;

  constexpr int KSEG = (MODE == 4) ? 1024 : 512;
  constexpr int NK = KSEG / 32;

  f32x4 acc[4][4];
#pragma unroll
  for (int i = 0; i < 4; ++i)
#pragma unroll
    for (int j = 0; j < 4; ++j) acc[i][j] = (f32x4){0.f, 0.f, 0.f, 0.f};

  const unsigned short* Ab;
  const unsigned short* Bb;
  if constexpr (MODE == 0 || MODE == 1 || MODE == 5) {
    Ab = A + (size_t)bx * 128 * 512;
    Bb = B + (size_t)by * 128 * 512;
  } else if constexpr (MODE == 2) {
    Ab = A + (size_t)bz * 524288 + (size_t)bx * 128 * 512;
    Bb = B + (size_t)bz * 524288 + (size_t)by * 128 * 512;
  } else {  // MODE 4: A=P[z] LD1024, B=VT[z] LD1024
    Ab = A + (size_t)bz * 1048576 + (size_t)bx * 128 * 1024;
    Bb = B + (size_t)bz * 524288 + (size_t)by * 128 * 1024;
  }

#define STAGE(buf, kc)                                             \
  {                                                                \
    _Pragma("unroll") for (int is = 0; is < 2; ++is) {             \
      int c = is * 256 + tid;                                      \
      int row = c >> 2, col = (c & 3) << 3;                        \
      GLD16(Ab + (size_t)row * KSEG + (kc)*32 + col,               \
            (char*)As[buf] + is * 4096 + wid * 1024);              \
      GLD16(Bb + (size_t)row * KSEG + (kc)*32 + col,               \
            (char*)Bs[buf] + is * 4096 + wid * 1024);              \
    }                                                              \
  }

  STAGE(0, 0);
  int cur = 0;
#pragma unroll 4
  for (int kc = 0; kc < NK; ++kc) {
    __syncthreads();  // buf[cur] staged (vmcnt drained), prev reads done
    if (kc + 1 < NK) STAGE(cur ^ 1, kc + 1);  // prefetch hides under compute
    bf16x8 af[4], bf_[4];
#pragma unroll
    for (int f = 0; f < 4; ++f) {
      af[f] = *(const bf16x8*)((const char*)As[cur] +
                               ((wr * 64 + f * 16 + l15) << 6) + (l4 << 4));
      bf_[f] = *(const bf16x8*)((const char*)Bs[cur] +
                                ((wc * 64 + f * 16 + l15) << 6) + (l4 << 4));
    }
#pragma unroll
    for (int mf = 0; mf < 4; ++mf)
#pragma unroll
      for (int nf = 0; nf < 4; ++nf)
        acc[mf][nf] = __builtin_amdgcn_mfma_f32_16x16x32_bf16(
            af[mf], bf_[nf], acc[mf][nf], 0, 0, 0);
    cur ^= 1;
  }
#undef STAGE

  // epilogue; C/D layout (validated): col = lane&15, row = (lane>>4)*4 + reg
  const int r0 = l4 * 4;
  const int c0 = l15;

#pragma unroll
  for (int nf = 0; nf < 4; ++nf) {
    int c_ = by * 128 + wc * 64 + nf * 16 + c0;
    float bvl = 0.f;
    if constexpr (MODE == 0 || MODE == 1 || MODE == 5) bvl = bias[c_] * bscale;
#pragma unroll
    for (int mf = 0; mf < 4; ++mf) {
      int rb = bx * 128 + wr * 64 + mf * 16 + r0;
#pragma unroll
      for (int r = 0; r < 4; ++r) {
        int r_ = rb + r;
        float v = acc[mf][nf][r];
        if constexpr (MODE == 0) {  // [nl][h][s][e], M=2048
          int nl = r_ >> 10, s = r_ & 1023;
          int h = c_ >> 9, e = c_ & 511;
          outb[(((size_t)nl * 8 + h) * 1024 + s) * 512 + e] = f2b(v + bvl);
        } else if constexpr (MODE == 1) {  // VT [nl][h][e][s]
          int nl = r_ >> 10, s = r_ & 1023;
          int h = c_ >> 9, e = c_ & 511;
          outb[(((size_t)nl * 8 + h) * 512 + e) * 1024 + s] = f2b(v + bvl);
        } else if constexpr (MODE == 2) {  // P[z][q][l], int32 mask
          int mv = maskI[(size_t)(n0 + (bz >> 3)) * 1048576 +
                         (size_t)r_ * 1024 + c_];
          outb[(size_t)bz * 1048576 + (size_t)r_ * 1024 + c_] =
              mv ? f2b(v) : (unsigned short)0;
        } else if constexpr (MODE == 4) {  // Ah[z][q][e]
          outb[(size_t)bz * 524288 + (size_t)r_ * 512 + c_] = f2b(v);
        } else {  // MODE 5: fp32 out + bias
          outf[(size_t)r_ * 512 + c_] = v + bvl;
        }
      }
    }
  }
}

extern "C" void kernel_launch(void* const* d_in, const int* in_sizes, int n_in,
                              void* d_out, int out_size, void* d_ws,
                              size_t ws_size, hipStream_t stream) {
  const float* values = (const float*)d_in[0];
  const float* keys = (const float*)d_in[1];
  const float* query = (const float*)d_in[2];
  const int* maskI = (const int*)d_in[4];
  const float* Wv = (const float*)d_in[5];
  const float* bv = (const float*)d_in[6];
  const float* Wk = (const float*)d_in[7];
  const float* bk = (const float*)d_in[8];
  const float* Wq = (const float*)d_in[9];
  const float* bq = (const float*)d_in[10];
  const float* Wo = (const float*)d_in[11];
  const float* bo = (const float*)d_in[12];
  float* dout = (float*)d_out;

  const int exp_sizes[13] = {4194304, 4194304, 4194304, 1024, 8388608,
                             2097152, 4096,    2097152, 4096, 2097152,
                             4096,    262144,  512};
  bool ok = (n_in == 13);
  if (ok)
    for (int i = 0; i < 13; ++i)
      if (in_sizes[i] != exp_sizes[i]) ok = false;
  if (!ok) {
    k_fill<<<512, 256, 0, stream>>>(dout, out_size, 1000.f);
    return;
  }

  // ---- workspace layout, BYTES ----
  char* w = (char*)d_ws;
  unsigned short* Wvb = (unsigned short*)(w);              //  4,194,304
  unsigned short* Wkb = (unsigned short*)(w + 4194304);    //  4,194,304
  unsigned short* Wqb = (unsigned short*)(w + 8388608);    //  4,194,304
  unsigned short* Wob = (unsigned short*)(w + 12582912);   //    524,288
  unsigned short* Atb = (unsigned short*)(w + 13107200);   //  8,388,608
  unsigned short* Q2 = (unsigned short*)(w + 21495808);    // 16,777,216 (2n)
  unsigned short* K2 = (unsigned short*)(w + 38273024);    // 16,777,216
  unsigned short* VT2 = (unsigned short*)(w + 55050240);   // 16,777,216
  unsigned short* P2 = (unsigned short*)(w + 71827456);    // 33,554,432
  // union region: Xc (conv, 6MB, live pre-proj) / Ah2 (16.7MB, live post-proj)
  unsigned short* Xcv = (unsigned short*)(w + 105381888);  //  2,097,152
  unsigned short* Xck = (unsigned short*)(w + 107479040);  //  2,097,152
  unsigned short* Xcq = (unsigned short*)(w + 109576192);  //  2,097,152
  unsigned short* Ah2 = (unsigned short*)(w + 105381888);  // 16,777,216
  const size_t need = 122159104;  // <= 127,438,848 proven available (r9)
  if (ws_size < need) {
    k_fill<<<512, 256, 0, stream>>>(dout, out_size, 2000.f);
    return;
  }

  // ---- weights -> bf16 (Wq scaled by 1/sqrt(E)) ----
  k_conv<<<512, 256, 0, stream>>>((const float4*)Wv, (ushort4*)Wvb, 524288,
                                  1.0f);
  k_conv<<<512, 256, 0, stream>>>((const float4*)Wk, (ushort4*)Wkb, 524288,
                                  1.0f);
  k_conv<<<512, 256, 0, stream>>>((const float4*)Wq, (ushort4*)Wqb, 524288,
                                  RS);
  k_conv<<<256, 256, 0, stream>>>((const float4*)Wo, (ushort4*)Wob, 65536,
                                  1.0f);

  // ---- 4 iterations x 2 batches ----
  for (int it = 0; it < 4; ++it) {
    const int n0 = it * 2;
    const size_t xoff = (size_t)n0 * 524288;  // floats per n
    k_conv<<<1024, 256, 0, stream>>>((const float4*)(values + xoff),
                                     (ushort4*)Xcv, 262144, 1.0f);
    k_conv<<<1024, 256, 0, stream>>>((const float4*)(keys + xoff),
                                     (ushort4*)Xck, 262144, 1.0f);
    k_conv<<<1024, 256, 0, stream>>>((const float4*)(query + xoff),
                                     (ushort4*)Xcq, 262144, 1.0f);
    // proj: M=2048, N=4096, K=512
    k_gemm<1><<<dim3(16, 32, 1), 256, 0, stream>>>(Xcv, Wvb, bv, 1.0f, nullptr,
                                                   VT2, nullptr, 0);
    k_gemm<0><<<dim3(16, 32, 1), 256, 0, stream>>>(Xck, Wkb, bk, 1.0f, nullptr,
                                                   K2, nullptr, 0);
    k_gemm<0><<<dim3(16, 32, 1), 256, 0, stream>>>(Xcq, Wqb, bq, RS, nullptr,
                                                   Q2, nullptr, 0);
    // energy: z = 16 (2n x 8h), 1024 blocks
    k_gemm<2><<<dim3(8, 8, 16), 256, 0, stream>>>(Q2, K2, nullptr, 0.f, maskI,
                                                  P2, nullptr, n0);
    // PV: z = 16, K=1024
    k_gemm<4><<<dim3(8, 4, 16), 256, 0, stream>>>(P2, VT2, nullptr, 0.f,
                                                  nullptr, Ah2, nullptr, 0);
    // head-sum per n
    k_reduce<<<512, 256, 0, stream>>>(Ah2, Atb + (size_t)n0 * 524288);
    k_reduce<<<512, 256, 0, stream>>>(Ah2 + 4194304,
                                      Atb + (size_t)(n0 + 1) * 524288);
  }

  // ---- final: [8192][512] @ Wo^T + bo -> fp32 d_out ----
  k_gemm<5><<<dim3(64, 4, 1), 256, 0, stream>>>(Atb, Wob, bo, 1.0f, nullptr,
                                                nullptr, dout, 0);
}

// Round 12
// 577.452 us; speedup vs baseline: 110.0769x; 1.1831x over previous
//
#include <hip/hip_runtime.h>

// ---------------------------------------------------------------------------
// ROUND 12: coalesced epilogues via LDS repack.
// r11 profile: energy/PV writes were 2-byte scatters -> WRITE 60MB vs 33.5
// ideal (RMW amplification), FETCH +36MB. Fix: after K-loop, stage the
// 128x128 result tile in LDS (stride 136 shorts, 16B-aligned rows; MODE 1
// writes transposed) and store full 16B chunks (256B contiguous per 16-lane
// group). MODE 5 (fp32) repacks in two 64-row passes. Core/grids unchanged.
// Pipeline (per 2n): conv -> proj Q/K/VT -> energy (+int32 mask) -> PV ->
// reduce -> final (+bo, fp32). Wq/bq carry 1/sqrt(E).
// ---------------------------------------------------------------------------

#define RS 0.04419417382415922f  // 1/sqrt(512)

typedef __attribute__((ext_vector_type(8))) short bf16x8;
typedef __attribute__((ext_vector_type(4))) float f32x4;

__device__ __forceinline__ unsigned short f2b(float f) {
  unsigned u = __builtin_bit_cast(unsigned, f);
  unsigned r = (u + 0x7FFFu + ((u >> 16) & 1u)) >> 16;  // RNE
  return (unsigned short)r;
}
__device__ __forceinline__ float b2f(unsigned short h) {
  return __builtin_bit_cast(float, ((unsigned)h) << 16);
}

__global__ void k_fill(float* p, int n, float v) {
  int i = blockIdx.x * blockDim.x + threadIdx.x;
  int stride = gridDim.x * blockDim.x;
  for (; i < n; i += stride) p[i] = v;
}

__global__ void k_conv(const float4* __restrict__ s, ushort4* __restrict__ d,
                       int n4, float scale) {
  int stride = gridDim.x * blockDim.x;
  for (int i = blockIdx.x * blockDim.x + threadIdx.x; i < n4; i += stride) {
    float4 v = s[i];
    ushort4 o;
    o.x = f2b(v.x * scale); o.y = f2b(v.y * scale);
    o.z = f2b(v.z * scale); o.w = f2b(v.w * scale);
    d[i] = o;
  }
}

// Sum 8 head-partials (bf16 [8][1024][512]) -> bf16 [1024][512] (one n).
__global__ void k_reduce(const unsigned short* __restrict__ a,
                         unsigned short* __restrict__ o) {
  int i = blockIdx.x * blockDim.x + threadIdx.x;  // 131072 ushort4 units
  const ushort4* av = (const ushort4*)a;
  float4 s = {0.f, 0.f, 0.f, 0.f};
#pragma unroll
  for (int h = 0; h < 8; ++h) {
    ushort4 v = av[h * 131072 + i];
    s.x += b2f(v.x); s.y += b2f(v.y); s.z += b2f(v.z); s.w += b2f(v.w);
  }
  ushort4 r;
  r.x = f2b(s.x); r.y = f2b(s.y); r.z = f2b(s.z); r.w = f2b(s.w);
  ((ushort4*)o)[i] = r;
}

#define GLD16(gp, sp)                                              \
  __builtin_amdgcn_global_load_lds(                                \
      (const __attribute__((address_space(1))) void*)(gp),         \
      (__attribute__((address_space(3))) void*)(sp), 16, 0, 0)

// 128x128-tile GEMM, dbuf staging (1 barrier/K-step), LDS-repacked epilogue.
// MODE: 0 proj->[nl][h][s][e] | 1 proj->VT [nl][h][e][s] (M=2048)
//       2 energy->P[z][q][l] (z<16, int32 mask) | 4 PV->Ah[z][q][e] (K=1024)
//       5 final -> fp32 d_out (+bias)
template <int MODE>
__global__ __launch_bounds__(256) void k_gemm(
    const unsigned short* __restrict__ A, const unsigned short* __restrict__ B,
    const float* __restrict__ bias, float bscale, const int* __restrict__ maskI,
    unsigned short* __restrict__ outb, float* __restrict__ outf, int n0) {
  // 34816B: staging = 4 x 8KB (A0,A1,B0,B1); repack tile reuses all of it.
  __shared__ short smem[17408];
  char* const sb = (char*)smem;

  const int tid = threadIdx.x;
  const int wid = tid >> 6;
  const int lane = tid & 63;
  const int wr = wid >> 1, wc = wid & 1;
  const int l15 = lane & 15, l4 = lane >> 4;
  const int bx = blockIdx.x, by = blockIdx.y, bz = blockIdx.z;

  constexpr int KSEG = (MODE == 4) ? 1024 : 512;
  constexpr int NK = KSEG / 32;

  f32x4 acc[4][4];
#pragma unroll
  for (int i = 0; i < 4; ++i)
#pragma unroll
    for (int j = 0; j < 4; ++j) acc[i][j] = (f32x4){0.f, 0.f, 0.f, 0.f};

  const unsigned short* Ab;
  const unsigned short* Bb;
  if constexpr (MODE == 0 || MODE == 1 || MODE == 5) {
    Ab = A + (size_t)bx * 128 * 512;
    Bb = B + (size_t)by * 128 * 512;
  } else if constexpr (MODE == 2) {
    Ab = A + (size_t)bz * 524288 + (size_t)bx * 128 * 512;
    Bb = B + (size_t)bz * 524288 + (size_t)by * 128 * 512;
  } else {  // MODE 4: A=P[z] LD1024, B=VT[z] LD1024
    Ab = A + (size_t)bz * 1048576 + (size_t)bx * 128 * 1024;
    Bb = B + (size_t)bz * 524288 + (size_t)by * 128 * 1024;
  }

#define STAGE(buf, kc)                                             \
  {                                                                \
    _Pragma("unroll") for (int is = 0; is < 2; ++is) {             \
      int c = is * 256 + tid;                                      \
      int row = c >> 2, col = (c & 3) << 3;                        \
      GLD16(Ab + (size_t)row * KSEG + (kc)*32 + col,               \
            sb + (buf)*8192 + is * 4096 + wid * 1024);             \
      GLD16(Bb + (size_t)row * KSEG + (kc)*32 + col,               \
            sb + 16384 + (buf)*8192 + is * 4096 + wid * 1024);     \
    }                                                              \
  }

  STAGE(0, 0);
  int cur = 0;
#pragma unroll 4
  for (int kc = 0; kc < NK; ++kc) {
    __syncthreads();  // buf[cur] staged, previous reads done
    if (kc + 1 < NK) STAGE(cur ^ 1, kc + 1);
    bf16x8 af[4], bf_[4];
#pragma unroll
    for (int f = 0; f < 4; ++f) {
      af[f] = *(const bf16x8*)(sb + cur * 8192 +
                               ((wr * 64 + f * 16 + l15) << 6) + (l4 << 4));
      bf_[f] = *(const bf16x8*)(sb + 16384 + cur * 8192 +
                                ((wc * 64 + f * 16 + l15) << 6) + (l4 << 4));
    }
#pragma unroll
    for (int mf = 0; mf < 4; ++mf)
#pragma unroll
      for (int nf = 0; nf < 4; ++nf)
        acc[mf][nf] = __builtin_amdgcn_mfma_f32_16x16x32_bf16(
            af[mf], bf_[nf], acc[mf][nf], 0, 0, 0);
    cur ^= 1;
  }
#undef STAGE

  // ---- epilogue: LDS repack -> coalesced 16B stores ----
  // C/D layout (validated): col = lane&15, row = (lane>>4)*4 + reg
  const int r0 = l4 * 4;
  const int c0 = l15;

  if constexpr (MODE != 5) {
    __syncthreads();  // all staging reads done; reuse smem as Cs[128][136]
#pragma unroll
    for (int nf = 0; nf < 4; ++nf) {
      int c_loc = wc * 64 + nf * 16 + c0;
      int c_ = by * 128 + c_loc;
      float bvl = 0.f;
      if constexpr (MODE == 0 || MODE == 1) bvl = bias[c_] * bscale;
#pragma unroll
      for (int mf = 0; mf < 4; ++mf) {
#pragma unroll
        for (int r = 0; r < 4; ++r) {
          int r_loc = wr * 64 + mf * 16 + r0 + r;
          float v = acc[mf][nf][r] + bvl;
          unsigned short bb;
          if constexpr (MODE == 2) {
            int r_ = bx * 128 + r_loc;
            int mv = maskI[(size_t)(n0 + (bz >> 3)) * 1048576 +
                           (size_t)r_ * 1024 + c_];
            bb = mv ? f2b(v) : (unsigned short)0;
          } else {
            bb = f2b(v);
          }
          if constexpr (MODE == 1)
            smem[c_loc * 136 + r_loc] = (short)bb;  // transposed tile
          else
            smem[r_loc * 136 + c_loc] = (short)bb;
        }
      }
    }
    __syncthreads();
    // 2048 chunks of 8 bf16; 16 chunks/row; 256B contiguous per 16 lanes
#pragma unroll
    for (int ch = 0; ch < 8; ++ch) {
      int idx = ch * 256 + tid;
      int row = idx >> 4;
      int col = (idx & 15) << 3;
      bf16x8 v = *(const bf16x8*)(smem + row * 136 + col);
      if constexpr (MODE == 0) {  // [nl][h][s][e]
        int r_ = bx * 128 + row, cB = by * 128 + col;
        int nl = r_ >> 10, s = r_ & 1023, h = cB >> 9, e = cB & 511;
        *(bf16x8*)(outb + (((size_t)nl * 8 + h) * 1024 + s) * 512 + e) = v;
      } else if constexpr (MODE == 1) {  // VT [nl][h][e][s]; Cs rows = e
        int cB = by * 128 + row;          // e-dim
        int r_ = bx * 128 + col;          // s-dim (8 contiguous)
        int nl = r_ >> 10, s = r_ & 1023, h = cB >> 9, e = cB & 511;
        *(bf16x8*)(outb + (((size_t)nl * 8 + h) * 512 + e) * 1024 + s) = v;
      } else if constexpr (MODE == 2) {  // P[z][q][l]
        int r_ = bx * 128 + row, cB = by * 128 + col;
        *(bf16x8*)(outb + (size_t)bz * 1048576 + (size_t)r_ * 1024 + cB) = v;
      } else {  // MODE 4: Ah[z][q][e]
        int r_ = bx * 128 + row, cB = by * 128 + col;
        *(bf16x8*)(outb + (size_t)bz * 524288 + (size_t)r_ * 512 + cB) = v;
      }
    }
  } else {
    // MODE 5: fp32 tile, two 64-row passes through Cs32[64][136]
    float* const Cs32 = (float*)smem;
#pragma unroll
    for (int hh = 0; hh < 2; ++hh) {
      __syncthreads();
      if (wr == hh) {
#pragma unroll
        for (int nf = 0; nf < 4; ++nf) {
          int c_loc = wc * 64 + nf * 16 + c0;
          float bvl = bias[by * 128 + c_loc];
#pragma unroll
          for (int mf = 0; mf < 4; ++mf)
#pragma unroll
            for (int r = 0; r < 4; ++r) {
              int rl = mf * 16 + r0 + r;  // 0..63 within half
              Cs32[rl * 136 + c_loc] = acc[mf][nf][r] + bvl;
            }
        }
      }
      __syncthreads();
#pragma unroll
      for (int ch = 0; ch < 8; ++ch) {
        int idx = ch * 256 + tid;   // 2048 float4 chunks
        int row = idx >> 5;          // 0..63
        int col = (idx & 31) << 2;   // 0..124
        float4 v = *(const float4*)(Cs32 + row * 136 + col);
        *(float4*)(outf + (size_t)(bx * 128 + hh * 64 + row) * 512 +
                   by * 128 + col) = v;
      }
    }
  }
}

extern "C" void kernel_launch(void* const* d_in, const int* in_sizes, int n_in,
                              void* d_out, int out_size, void* d_ws,
                              size_t ws_size, hipStream_t stream) {
  const float* values = (const float*)d_in[0];
  const float* keys = (const float*)d_in[1];
  const float* query = (const float*)d_in[2];
  const int* maskI = (const int*)d_in[4];
  const float* Wv = (const float*)d_in[5];
  const float* bv = (const float*)d_in[6];
  const float* Wk = (const float*)d_in[7];
  const float* bk = (const float*)d_in[8];
  const float* Wq = (const float*)d_in[9];
  const float* bq = (const float*)d_in[10];
  const float* Wo = (const float*)d_in[11];
  const float* bo = (const float*)d_in[12];
  float* dout = (float*)d_out;

  const int exp_sizes[13] = {4194304, 4194304, 4194304, 1024, 8388608,
                             2097152, 4096,    2097152, 4096, 2097152,
                             4096,    262144,  512};
  bool ok = (n_in == 13);
  if (ok)
    for (int i = 0; i < 13; ++i)
      if (in_sizes[i] != exp_sizes[i]) ok = false;
  if (!ok) {
    k_fill<<<512, 256, 0, stream>>>(dout, out_size, 1000.f);
    return;
  }

  // ---- workspace layout, BYTES ----
  char* w = (char*)d_ws;
  unsigned short* Wvb = (unsigned short*)(w);              //  4,194,304
  unsigned short* Wkb = (unsigned short*)(w + 4194304);    //  4,194,304
  unsigned short* Wqb = (unsigned short*)(w + 8388608);    //  4,194,304
  unsigned short* Wob = (unsigned short*)(w + 12582912);   //    524,288
  unsigned short* Atb = (unsigned short*)(w + 13107200);   //  8,388,608
  unsigned short* Q2 = (unsigned short*)(w + 21495808);    // 16,777,216 (2n)
  unsigned short* K2 = (unsigned short*)(w + 38273024);    // 16,777,216
  unsigned short* VT2 = (unsigned short*)(w + 55050240);   // 16,777,216
  unsigned short* P2 = (unsigned short*)(w + 71827456);    // 33,554,432
  unsigned short* Xcv = (unsigned short*)(w + 105381888);  //  2,097,152
  unsigned short* Xck = (unsigned short*)(w + 107479040);  //  2,097,152
  unsigned short* Xcq = (unsigned short*)(w + 109576192);  //  2,097,152
  unsigned short* Ah2 = (unsigned short*)(w + 105381888);  // 16,777,216 (alias)
  const size_t need = 122159104;  // <= 127,438,848 proven available (r9)
  if (ws_size < need) {
    k_fill<<<512, 256, 0, stream>>>(dout, out_size, 2000.f);
    return;
  }

  // ---- weights -> bf16 (Wq scaled by 1/sqrt(E)) ----
  k_conv<<<512, 256, 0, stream>>>((const float4*)Wv, (ushort4*)Wvb, 524288,
                                  1.0f);
  k_conv<<<512, 256, 0, stream>>>((const float4*)Wk, (ushort4*)Wkb, 524288,
                                  1.0f);
  k_conv<<<512, 256, 0, stream>>>((const float4*)Wq, (ushort4*)Wqb, 524288,
                                  RS);
  k_conv<<<256, 256, 0, stream>>>((const float4*)Wo, (ushort4*)Wob, 65536,
                                  1.0f);

  // ---- 4 iterations x 2 batches ----
  for (int it = 0; it < 4; ++it) {
    const int n0 = it * 2;
    const size_t xoff = (size_t)n0 * 524288;  // floats per n
    k_conv<<<1024, 256, 0, stream>>>((const float4*)(values + xoff),
                                     (ushort4*)Xcv, 262144, 1.0f);
    k_conv<<<1024, 256, 0, stream>>>((const float4*)(keys + xoff),
                                     (ushort4*)Xck, 262144, 1.0f);
    k_conv<<<1024, 256, 0, stream>>>((const float4*)(query + xoff),
                                     (ushort4*)Xcq, 262144, 1.0f);
    // proj: M=2048, N=4096, K=512
    k_gemm<1><<<dim3(16, 32, 1), 256, 0, stream>>>(Xcv, Wvb, bv, 1.0f, nullptr,
                                                   VT2, nullptr, 0);
    k_gemm<0><<<dim3(16, 32, 1), 256, 0, stream>>>(Xck, Wkb, bk, 1.0f, nullptr,
                                                   K2, nullptr, 0);
    k_gemm<0><<<dim3(16, 32, 1), 256, 0, stream>>>(Xcq, Wqb, bq, RS, nullptr,
                                                   Q2, nullptr, 0);
    // energy: z = 16 (2n x 8h)
    k_gemm<2><<<dim3(8, 8, 16), 256, 0, stream>>>(Q2, K2, nullptr, 0.f, maskI,
                                                  P2, nullptr, n0);
    // PV: z = 16, K=1024
    k_gemm<4><<<dim3(8, 4, 16), 256, 0, stream>>>(P2, VT2, nullptr, 0.f,
                                                  nullptr, Ah2, nullptr, 0);
    // head-sum per n
    k_reduce<<<512, 256, 0, stream>>>(Ah2, Atb + (size_t)n0 * 524288);
    k_reduce<<<512, 256, 0, stream>>>(Ah2 + 4194304,
                                      Atb + (size_t)(n0 + 1) * 524288);
  }

  // ---- final: [8192][512] @ Wo^T + bo -> fp32 d_out ----
  k_gemm<5><<<dim3(64, 4, 1), 256, 0, stream>>>(Atb, Wob, bo, 1.0f, nullptr,
                                                nullptr, dout, 0);
}